// Round 1
// baseline (722.784 us; speedup 1.0000x reference)
//
#include <hip/hip_runtime.h>

#define N_NODES 100000
#define N_EDGES 1600000
#define IN_DIM 256
#define HID 64
#define HEADS 2
#define HD 128
#define OUT_DIM 256
#define NEG_SLOPE 0.2f

// ---------------- GEMM: C[M,N] = A[M,K] @ B[K,N] (+bias, relu) ----------------
#define BM 128
#define BN 128
#define BK 32
#define APAD 4   // As stride = BM+APAD = 132 (keeps float4 alignment, breaks bank conflicts)

__global__ __launch_bounds__(256)
void gemm_f32(const float* __restrict__ A, const float* __restrict__ B,
              float* __restrict__ C, int M, int K, int N,
              const float* __restrict__ bias, int relu_flag)
{
    __shared__ float As[BK * (BM + APAD)];   // transposed: As[kk][m]
    __shared__ float Bs[BK * BN];            // Bs[kk][n]
    const int t  = threadIdx.x;
    const int tx = t & 15;
    const int ty = t >> 4;
    const int m0 = blockIdx.x * BM;
    const int n0 = blockIdx.y * BN;

    float acc[8][8];
#pragma unroll
    for (int i = 0; i < 8; i++)
#pragma unroll
        for (int j = 0; j < 8; j++) acc[i][j] = 0.f;

    for (int k0 = 0; k0 < K; k0 += BK) {
        // stage A tile (BM x BK), store transposed
#pragma unroll
        for (int i = 0; i < 4; i++) {
            int f = t + i * 256;
            int r = f >> 3;            // 0..127
            int c = (f & 7) * 4;       // 0..28
            int gr = m0 + r;
            if (gr > M - 1) gr = M - 1;
            float4 v = *reinterpret_cast<const float4*>(&A[(size_t)gr * K + k0 + c]);
            As[(c + 0) * (BM + APAD) + r] = v.x;
            As[(c + 1) * (BM + APAD) + r] = v.y;
            As[(c + 2) * (BM + APAD) + r] = v.z;
            As[(c + 3) * (BM + APAD) + r] = v.w;
        }
        // stage B tile (BK x BN)
#pragma unroll
        for (int i = 0; i < 4; i++) {
            int f  = t + i * 256;
            int kk = f >> 5;           // 0..31
            int n4 = (f & 31) * 4;     // 0..124
            *reinterpret_cast<float4*>(&Bs[kk * BN + n4]) =
                *reinterpret_cast<const float4*>(&B[(size_t)(k0 + kk) * N + n0 + n4]);
        }
        __syncthreads();
#pragma unroll
        for (int kk = 0; kk < BK; kk++) {
            float4 a0 = *reinterpret_cast<const float4*>(&As[kk * (BM + APAD) + ty * 4]);
            float4 a1 = *reinterpret_cast<const float4*>(&As[kk * (BM + APAD) + 64 + ty * 4]);
            float4 b0 = *reinterpret_cast<const float4*>(&Bs[kk * BN + tx * 4]);
            float4 b1 = *reinterpret_cast<const float4*>(&Bs[kk * BN + 64 + tx * 4]);
            float a[8] = {a0.x, a0.y, a0.z, a0.w, a1.x, a1.y, a1.z, a1.w};
            float b[8] = {b0.x, b0.y, b0.z, b0.w, b1.x, b1.y, b1.z, b1.w};
#pragma unroll
            for (int i = 0; i < 8; i++)
#pragma unroll
                for (int j = 0; j < 8; j++)
                    acc[i][j] = fmaf(a[i], b[j], acc[i][j]);
        }
        __syncthreads();
    }

#pragma unroll
    for (int i = 0; i < 8; i++) {
        int row = m0 + ((i < 4) ? (ty * 4 + i) : (64 + ty * 4 + i - 4));
        if (row >= M) continue;
#pragma unroll
        for (int cj = 0; cj < 2; cj++) {
            int col = n0 + ((cj == 0) ? tx * 4 : 64 + tx * 4);
            float4 v;
            v.x = acc[i][cj * 4 + 0];
            v.y = acc[i][cj * 4 + 1];
            v.z = acc[i][cj * 4 + 2];
            v.w = acc[i][cj * 4 + 3];
            if (bias) {
                v.x += bias[col + 0]; v.y += bias[col + 1];
                v.z += bias[col + 2]; v.w += bias[col + 3];
            }
            if (relu_flag) {
                v.x = fmaxf(v.x, 0.f); v.y = fmaxf(v.y, 0.f);
                v.z = fmaxf(v.z, 0.f); v.w = fmaxf(v.w, 0.f);
            }
            *reinterpret_cast<float4*>(&C[(size_t)row * N + col]) = v;
        }
    }
}

// ---------------- el/er: one wave per node ----------------
__global__ __launch_bounds__(256)
void elr_kernel(const float* __restrict__ h, const float* __restrict__ attn_l,
                const float* __restrict__ attn_r, float* __restrict__ el,
                float* __restrict__ er)
{
    int w    = (int)((blockIdx.x * blockDim.x + threadIdx.x) >> 6);
    int lane = threadIdx.x & 63;
    if (w >= N_NODES) return;
    float h0 = h[(size_t)w * HD + lane];
    float h1 = h[(size_t)w * HD + 64 + lane];
    float v0 = h0 * attn_l[lane];
    float v1 = h1 * attn_l[64 + lane];
    float v2 = h0 * attn_r[lane];
    float v3 = h1 * attn_r[64 + lane];
#pragma unroll
    for (int o = 32; o; o >>= 1) {
        v0 += __shfl_xor(v0, o);
        v1 += __shfl_xor(v1, o);
        v2 += __shfl_xor(v2, o);
        v3 += __shfl_xor(v3, o);
    }
    if (lane == 0) {
        el[w * 2 + 0] = v0; el[w * 2 + 1] = v1;
        er[w * 2 + 0] = v2; er[w * 2 + 1] = v3;
    }
}

// ---------------- CSR build ----------------
__global__ void deg_kernel(const int* __restrict__ dst, int* __restrict__ deg)
{
    int i = blockIdx.x * blockDim.x + threadIdx.x;
    if (i < N_EDGES) atomicAdd(&deg[dst[i]], 1);
}

__global__ __launch_bounds__(1024)
void scan_kernel(const int* __restrict__ deg, int* __restrict__ row_ptr)
{
    __shared__ int sdata[1024];
    const int tid   = threadIdx.x;
    const int chunk = (N_NODES + 1023) / 1024;
    int s0 = tid * chunk;
    int s1 = s0 + chunk; if (s1 > N_NODES) s1 = N_NODES;
    int sum = 0;
    for (int i = s0; i < s1; i++) sum += deg[i];
    sdata[tid] = sum;
    __syncthreads();
    for (int off = 1; off < 1024; off <<= 1) {
        int v = 0;
        if (tid >= off) v = sdata[tid - off];
        __syncthreads();
        sdata[tid] += v;
        __syncthreads();
    }
    int run = (tid == 0) ? 0 : sdata[tid - 1];
    for (int i = s0; i < s1; i++) { row_ptr[i] = run; run += deg[i]; }
    if (tid == 1023) row_ptr[N_NODES] = sdata[1023];
}

__global__ void scatter_kernel(const int* __restrict__ src, const int* __restrict__ dst,
                               const int* __restrict__ row_ptr, int* __restrict__ cursor,
                               int* __restrict__ sorted_src)
{
    int i = blockIdx.x * blockDim.x + threadIdx.x;
    if (i < N_EDGES) {
        int d = dst[i];
        int p = row_ptr[d] + atomicAdd(&cursor[d], 1);
        sorted_src[p] = src[i];
    }
}

// ---------------- per-node softmax + aggregation: one wave per node ----------------
__global__ __launch_bounds__(256)
void node_kernel(const float* __restrict__ h, const float* __restrict__ el,
                 const float* __restrict__ er, const int* __restrict__ row_ptr,
                 const int* __restrict__ sorted_src, float* __restrict__ ws_e,
                 const float* __restrict__ gat_bias, float* __restrict__ agg)
{
    int n    = (int)((blockIdx.x * blockDim.x + threadIdx.x) >> 6);
    int lane = threadIdx.x & 63;
    if (n >= N_NODES) return;
    int beg = row_ptr[n], end = row_ptr[n + 1];

    float er0 = er[n * 2 + 0], er1 = er[n * 2 + 1];

    // phase 1: logits + max
    float mx0 = -1e30f, mx1 = -1e30f;
    for (int i = beg + lane; i < end; i += 64) {
        int s = sorted_src[i];
        float e0 = el[s * 2 + 0] + er0;
        float e1 = el[s * 2 + 1] + er1;
        e0 = e0 > 0.f ? e0 : NEG_SLOPE * e0;
        e1 = e1 > 0.f ? e1 : NEG_SLOPE * e1;
        ws_e[(size_t)i * 2 + 0] = e0;
        ws_e[(size_t)i * 2 + 1] = e1;
        mx0 = fmaxf(mx0, e0); mx1 = fmaxf(mx1, e1);
    }
#pragma unroll
    for (int o = 32; o; o >>= 1) {
        mx0 = fmaxf(mx0, __shfl_xor(mx0, o));
        mx1 = fmaxf(mx1, __shfl_xor(mx1, o));
    }

    // phase 2: exp + sum
    float s0 = 0.f, s1 = 0.f;
    for (int i = beg + lane; i < end; i += 64) {
        float ee0 = __expf(ws_e[(size_t)i * 2 + 0] - mx0);
        float ee1 = __expf(ws_e[(size_t)i * 2 + 1] - mx1);
        ws_e[(size_t)i * 2 + 0] = ee0;
        ws_e[(size_t)i * 2 + 1] = ee1;
        s0 += ee0; s1 += ee1;
    }
#pragma unroll
    for (int o = 32; o; o >>= 1) {
        s0 += __shfl_xor(s0, o);
        s1 += __shfl_xor(s1, o);
    }
    __threadfence_block();   // make ws_e stores visible across lanes

    // phase 3: weighted aggregation (lane owns dim d for both heads)
    float inv0 = s0 > 0.f ? 1.f / s0 : 0.f;
    float inv1 = s1 > 0.f ? 1.f / s1 : 0.f;
    float acc0 = 0.f, acc1 = 0.f;
    for (int e = beg; e < end; e++) {
        float2 ee = *reinterpret_cast<const float2*>(&ws_e[(size_t)e * 2]);
        int s = sorted_src[e];
        float a0 = ee.x * inv0;
        float a1 = ee.y * inv1;
        acc0 = fmaf(a0, h[(size_t)s * HD + lane], acc0);
        acc1 = fmaf(a1, h[(size_t)s * HD + 64 + lane], acc1);
    }
    float o0 = acc0 + gat_bias[lane];
    float o1 = acc1 + gat_bias[64 + lane];
    agg[(size_t)n * HD + lane]      = fmaxf(o0, 0.f);
    agg[(size_t)n * HD + 64 + lane] = fmaxf(o1, 0.f);
}

// ---------------- launch ----------------
extern "C" void kernel_launch(void* const* d_in, const int* in_sizes, int n_in,
                              void* d_out, int out_size, void* d_ws, size_t ws_size,
                              hipStream_t stream)
{
    const float* feat     = (const float*)d_in[0];
    const int*   src      = (const int*)d_in[1];
    const int*   dst      = (const int*)d_in[2];
    const float* W        = (const float*)d_in[3];
    const float* attn_l   = (const float*)d_in[4];
    const float* attn_r   = (const float*)d_in[5];
    const float* gat_bias = (const float*)d_in[6];
    const float* lin_W    = (const float*)d_in[7];
    const float* lin_b    = (const float*)d_in[8];
    float* out = (float*)d_out;

    char* ws = (char*)d_ws;
    float* h      = (float*)(ws + 0);            //  51,200,000 B
    float* agg    = (float*)(ws + 51200000);     //  51,200,000 B
    float* ws_e   = (float*)(ws + 102400000);    //  12,800,000 B
    int*   ssrc   = (int*)  (ws + 115200000);    //   6,400,000 B
    float* el     = (float*)(ws + 121600000);    //     800,000 B
    float* er     = (float*)(ws + 122400000);    //     800,000 B
    int*   deg    = (int*)  (ws + 123200000);    //     400,000 B
    int*   cursor = (int*)  (ws + 123600000);    //     400,000 B
    int*   rowptr = (int*)  (ws + 124000000);    //     400,004 B

    hipMemsetAsync(deg, 0, 800000, stream);      // deg + cursor

    dim3 blk(256);
    dim3 g1((N_NODES + BM - 1) / BM, 1);
    gemm_f32<<<g1, blk, 0, stream>>>(feat, W, h, N_NODES, IN_DIM, HD, nullptr, 0);

    elr_kernel<<<(N_NODES + 3) / 4, 256, 0, stream>>>(h, attn_l, attn_r, el, er);

    deg_kernel<<<(N_EDGES + 255) / 256, 256, 0, stream>>>(dst, deg);
    scan_kernel<<<1, 1024, 0, stream>>>(deg, rowptr);
    scatter_kernel<<<(N_EDGES + 255) / 256, 256, 0, stream>>>(src, dst, rowptr, cursor, ssrc);

    node_kernel<<<(N_NODES + 3) / 4, 256, 0, stream>>>(h, el, er, rowptr, ssrc, ws_e,
                                                       gat_bias, agg);

    dim3 g2((N_NODES + BM - 1) / BM, OUT_DIM / BN);
    gemm_f32<<<g2, blk, 0, stream>>>(agg, lin_W, out, N_NODES, HD, OUT_DIM, lin_b, 1);
}

// Round 2
// 628.129 us; speedup vs baseline: 1.1507x; 1.1507x over previous
//
#include <hip/hip_runtime.h>

#define N_NODES 100000
#define N_EDGES 1600000
#define IN_DIM 256
#define HID 64
#define HEADS 2
#define HD 128
#define OUT_DIM 256
#define NEG_SLOPE 0.2f

typedef unsigned int uint32;
typedef unsigned short ushort16;

__device__ __forceinline__ ushort16 f2bf(float f) {
    union { float f; uint32 u; } v; v.f = f;
    uint32 u = v.u;
    return (ushort16)((u + 0x7FFFu + ((u >> 16) & 1u)) >> 16);  // RNE
}
__device__ __forceinline__ float bf2f(ushort16 b) {
    union { uint32 u; float f; } v; v.u = ((uint32)b) << 16;
    return v.f;
}

// ---------------- GEMM: C[M,N] = A[M,K] @ B[K,N] (+bias, relu) ----------------
#define BM 128
#define BN 128
#define BK 32
#define APAD 4

template <int BF16OUT>
__global__ __launch_bounds__(256)
void gemm_f32(const float* __restrict__ A, const float* __restrict__ B,
              void* __restrict__ Cout, int M, int K, int N,
              const float* __restrict__ bias, int relu_flag)
{
    __shared__ float As[BK * (BM + APAD)];   // transposed: As[kk][m]
    __shared__ float Bs[BK * BN];            // Bs[kk][n]
    const int t  = threadIdx.x;
    const int tx = t & 15;
    const int ty = t >> 4;
    const int m0 = blockIdx.x * BM;
    const int n0 = blockIdx.y * BN;

    float acc[8][8];
#pragma unroll
    for (int i = 0; i < 8; i++)
#pragma unroll
        for (int j = 0; j < 8; j++) acc[i][j] = 0.f;

    for (int k0 = 0; k0 < K; k0 += BK) {
#pragma unroll
        for (int i = 0; i < 4; i++) {
            int f = t + i * 256;
            int r = f >> 3;
            int c = (f & 7) * 4;
            int gr = m0 + r;
            if (gr > M - 1) gr = M - 1;
            float4 v = *reinterpret_cast<const float4*>(&A[(size_t)gr * K + k0 + c]);
            As[(c + 0) * (BM + APAD) + r] = v.x;
            As[(c + 1) * (BM + APAD) + r] = v.y;
            As[(c + 2) * (BM + APAD) + r] = v.z;
            As[(c + 3) * (BM + APAD) + r] = v.w;
        }
#pragma unroll
        for (int i = 0; i < 4; i++) {
            int f  = t + i * 256;
            int kk = f >> 5;
            int n4 = (f & 31) * 4;
            *reinterpret_cast<float4*>(&Bs[kk * BN + n4]) =
                *reinterpret_cast<const float4*>(&B[(size_t)(k0 + kk) * N + n0 + n4]);
        }
        __syncthreads();
#pragma unroll
        for (int kk = 0; kk < BK; kk++) {
            float4 a0 = *reinterpret_cast<const float4*>(&As[kk * (BM + APAD) + ty * 4]);
            float4 a1 = *reinterpret_cast<const float4*>(&As[kk * (BM + APAD) + 64 + ty * 4]);
            float4 b0 = *reinterpret_cast<const float4*>(&Bs[kk * BN + tx * 4]);
            float4 b1 = *reinterpret_cast<const float4*>(&Bs[kk * BN + 64 + tx * 4]);
            float a[8] = {a0.x, a0.y, a0.z, a0.w, a1.x, a1.y, a1.z, a1.w};
            float b[8] = {b0.x, b0.y, b0.z, b0.w, b1.x, b1.y, b1.z, b1.w};
#pragma unroll
            for (int i = 0; i < 8; i++)
#pragma unroll
                for (int j = 0; j < 8; j++)
                    acc[i][j] = fmaf(a[i], b[j], acc[i][j]);
        }
        __syncthreads();
    }

#pragma unroll
    for (int i = 0; i < 8; i++) {
        int row = m0 + ((i < 4) ? (ty * 4 + i) : (64 + ty * 4 + i - 4));
        if (row >= M) continue;
#pragma unroll
        for (int cj = 0; cj < 2; cj++) {
            int col = n0 + ((cj == 0) ? tx * 4 : 64 + tx * 4);
            float4 v;
            v.x = acc[i][cj * 4 + 0];
            v.y = acc[i][cj * 4 + 1];
            v.z = acc[i][cj * 4 + 2];
            v.w = acc[i][cj * 4 + 3];
            if (bias) {
                v.x += bias[col + 0]; v.y += bias[col + 1];
                v.z += bias[col + 2]; v.w += bias[col + 3];
            }
            if (relu_flag) {
                v.x = fmaxf(v.x, 0.f); v.y = fmaxf(v.y, 0.f);
                v.z = fmaxf(v.z, 0.f); v.w = fmaxf(v.w, 0.f);
            }
            if (BF16OUT) {
                ushort16* C = (ushort16*)Cout;
                uint2 p;
                p.x = (uint32)f2bf(v.x) | ((uint32)f2bf(v.y) << 16);
                p.y = (uint32)f2bf(v.z) | ((uint32)f2bf(v.w) << 16);
                *reinterpret_cast<uint2*>(&C[(size_t)row * N + col]) = p;
            } else {
                float* C = (float*)Cout;
                *reinterpret_cast<float4*>(&C[(size_t)row * N + col]) = v;
            }
        }
    }
}

// ---------------- el/er from bf16 h: one wave per node ----------------
__global__ __launch_bounds__(256)
void elr_kernel(const ushort16* __restrict__ hb, const float* __restrict__ attn_l,
                const float* __restrict__ attn_r, float* __restrict__ el,
                float* __restrict__ er)
{
    int w    = (int)((blockIdx.x * blockDim.x + threadIdx.x) >> 6);
    int lane = threadIdx.x & 63;
    if (w >= N_NODES) return;
    float h0 = bf2f(hb[(size_t)w * HD + lane]);
    float h1 = bf2f(hb[(size_t)w * HD + 64 + lane]);
    float v0 = h0 * attn_l[lane];
    float v1 = h1 * attn_l[64 + lane];
    float v2 = h0 * attn_r[lane];
    float v3 = h1 * attn_r[64 + lane];
#pragma unroll
    for (int o = 32; o; o >>= 1) {
        v0 += __shfl_xor(v0, o);
        v1 += __shfl_xor(v1, o);
        v2 += __shfl_xor(v2, o);
        v3 += __shfl_xor(v3, o);
    }
    if (lane == 0) {
        el[w * 2 + 0] = v0; el[w * 2 + 1] = v1;
        er[w * 2 + 0] = v2; er[w * 2 + 1] = v3;
    }
}

// ---------------- CSR build ----------------
__global__ void deg_kernel(const int* __restrict__ dst, int* __restrict__ deg)
{
    int i = blockIdx.x * blockDim.x + threadIdx.x;
    if (i < N_EDGES) atomicAdd(&deg[dst[i]], 1);
}

__global__ __launch_bounds__(1024)
void scan_kernel(const int* __restrict__ deg, int* __restrict__ row_ptr)
{
    __shared__ int sdata[1024];
    const int tid   = threadIdx.x;
    const int chunk = (N_NODES + 1023) / 1024;
    int s0 = tid * chunk;
    int s1 = s0 + chunk; if (s1 > N_NODES) s1 = N_NODES;
    int sum = 0;
    for (int i = s0; i < s1; i++) sum += deg[i];
    sdata[tid] = sum;
    __syncthreads();
    for (int off = 1; off < 1024; off <<= 1) {
        int v = 0;
        if (tid >= off) v = sdata[tid - off];
        __syncthreads();
        sdata[tid] += v;
        __syncthreads();
    }
    int run = (tid == 0) ? 0 : sdata[tid - 1];
    for (int i = s0; i < s1; i++) { row_ptr[i] = run; run += deg[i]; }
    if (tid == 1023) row_ptr[N_NODES] = sdata[1023];
}

__global__ void scatter_kernel(const int* __restrict__ src, const int* __restrict__ dst,
                               const int* __restrict__ row_ptr, int* __restrict__ cursor,
                               int* __restrict__ sorted_src)
{
    int i = blockIdx.x * blockDim.x + threadIdx.x;
    if (i < N_EDGES) {
        int d = dst[i];
        int p = row_ptr[d] + atomicAdd(&cursor[d], 1);
        sorted_src[p] = src[i];
    }
}

// ---------------- per-node softmax + aggregation: one wave per node ----------------
__global__ __launch_bounds__(256)
void node_kernel(const ushort16* __restrict__ hb, const float* __restrict__ el,
                 const float* __restrict__ er, const int* __restrict__ row_ptr,
                 const int* __restrict__ sorted_src, float* __restrict__ ws_e,
                 const float* __restrict__ gat_bias, float* __restrict__ agg)
{
    int n    = (int)((blockIdx.x * blockDim.x + threadIdx.x) >> 6);
    int lane = threadIdx.x & 63;
    if (n >= N_NODES) return;
    int beg = row_ptr[n], end = row_ptr[n + 1];

    float er0 = er[n * 2 + 0], er1 = er[n * 2 + 1];

    // phase 1: logits (stored raw) + online max/sum per lane
    float mx0 = -1e30f, mx1 = -1e30f, s0 = 0.f, s1 = 0.f;
    for (int i = beg + lane; i < end; i += 64) {
        int s = sorted_src[i];
        float2 elv = *reinterpret_cast<const float2*>(&el[s * 2]);
        float e0 = elv.x + er0; e0 = e0 > 0.f ? e0 : NEG_SLOPE * e0;
        float e1 = elv.y + er1; e1 = e1 > 0.f ? e1 : NEG_SLOPE * e1;
        float2 st; st.x = e0; st.y = e1;
        *reinterpret_cast<float2*>(&ws_e[(size_t)i * 2]) = st;
        float m0n = fmaxf(mx0, e0);
        s0 = s0 * __expf(mx0 - m0n) + __expf(e0 - m0n);
        mx0 = m0n;
        float m1n = fmaxf(mx1, e1);
        s1 = s1 * __expf(mx1 - m1n) + __expf(e1 - m1n);
        mx1 = m1n;
    }
    // cross-lane online-softmax merge
#pragma unroll
    for (int o = 32; o; o >>= 1) {
        float mo0 = __shfl_xor(mx0, o);
        float so0 = __shfl_xor(s0, o);
        float m0  = fmaxf(mx0, mo0);
        s0 = s0 * __expf(mx0 - m0) + so0 * __expf(mo0 - m0);
        mx0 = m0;
        float mo1 = __shfl_xor(mx1, o);
        float so1 = __shfl_xor(s1, o);
        float m1  = fmaxf(mx1, mo1);
        s1 = s1 * __expf(mx1 - m1) + so1 * __expf(mo1 - m1);
        mx1 = m1;
    }
    __threadfence_block();   // ws_e stores visible across lanes

    float inv0 = s0 > 0.f ? 1.f / s0 : 0.f;
    float inv1 = s1 > 0.f ? 1.f / s1 : 0.f;

    // phase 3: half-wave edge split. 32 lanes cover 128 dims (4 bf16 each).
    const int half = lane >> 5;
    const int j    = lane & 31;
    const bool hd1 = (j >= 16);
    const float mxh  = hd1 ? mx1 : mx0;
    const float invh = hd1 ? inv1 : inv0;
    float4 acc = {0.f, 0.f, 0.f, 0.f};

    int e = beg + half;
#define EDGE_BODY(E)                                                              \
    {                                                                             \
        float2 ev = *reinterpret_cast<const float2*>(&ws_e[(size_t)(E) * 2]);     \
        int s = sorted_src[(E)];                                                  \
        float a = __expf((hd1 ? ev.y : ev.x) - mxh) * invh;                       \
        uint2 hv = *reinterpret_cast<const uint2*>(&hb[(size_t)s * HD + 4 * j]);  \
        acc.x = fmaf(a, bf2f((ushort16)(hv.x & 0xffff)), acc.x);                  \
        acc.y = fmaf(a, bf2f((ushort16)(hv.x >> 16)),    acc.y);                  \
        acc.z = fmaf(a, bf2f((ushort16)(hv.y & 0xffff)), acc.z);                  \
        acc.w = fmaf(a, bf2f((ushort16)(hv.y >> 16)),    acc.w);                  \
    }
    for (; e + 2 < end; e += 4) { EDGE_BODY(e); EDGE_BODY(e + 2); }
    if (e < end) EDGE_BODY(e);
#undef EDGE_BODY

    // combine the two half-waves
    acc.x += __shfl_xor(acc.x, 32);
    acc.y += __shfl_xor(acc.y, 32);
    acc.z += __shfl_xor(acc.z, 32);
    acc.w += __shfl_xor(acc.w, 32);

    if (lane < 32) {
        float4 b = *reinterpret_cast<const float4*>(&gat_bias[4 * j]);
        float4 o;
        o.x = fmaxf(acc.x + b.x, 0.f);
        o.y = fmaxf(acc.y + b.y, 0.f);
        o.z = fmaxf(acc.z + b.z, 0.f);
        o.w = fmaxf(acc.w + b.w, 0.f);
        *reinterpret_cast<float4*>(&agg[(size_t)n * HD + 4 * j]) = o;
    }
}

// ---------------- launch ----------------
extern "C" void kernel_launch(void* const* d_in, const int* in_sizes, int n_in,
                              void* d_out, int out_size, void* d_ws, size_t ws_size,
                              hipStream_t stream)
{
    const float* feat     = (const float*)d_in[0];
    const int*   src      = (const int*)d_in[1];
    const int*   dst      = (const int*)d_in[2];
    const float* W        = (const float*)d_in[3];
    const float* attn_l   = (const float*)d_in[4];
    const float* attn_r   = (const float*)d_in[5];
    const float* gat_bias = (const float*)d_in[6];
    const float* lin_W    = (const float*)d_in[7];
    const float* lin_b    = (const float*)d_in[8];
    float* out = (float*)d_out;

    char* ws = (char*)d_ws;
    ushort16* hb  = (ushort16*)(ws + 0);          // 25,600,000 B
    float* agg    = (float*)(ws + 25600000);      // 51,200,000 B
    float* ws_e   = (float*)(ws + 76800000);      // 12,800,000 B
    int*   ssrc   = (int*)  (ws + 89600000);      //  6,400,000 B
    float* el     = (float*)(ws + 96000000);      //    800,000 B
    float* er     = (float*)(ws + 96800000);      //    800,000 B
    int*   deg    = (int*)  (ws + 97600000);      //    400,000 B
    int*   cursor = (int*)  (ws + 98000000);      //    400,000 B
    int*   rowptr = (int*)  (ws + 98400000);      //    400,004 B

    hipMemsetAsync(deg, 0, 800000, stream);       // deg + cursor

    dim3 blk(256);
    dim3 g1((N_NODES + BM - 1) / BM, 1);
    gemm_f32<1><<<g1, blk, 0, stream>>>(feat, W, hb, N_NODES, IN_DIM, HD, nullptr, 0);

    elr_kernel<<<(N_NODES + 3) / 4, 256, 0, stream>>>(hb, attn_l, attn_r, el, er);

    deg_kernel<<<(N_EDGES + 255) / 256, 256, 0, stream>>>(dst, deg);
    scan_kernel<<<1, 1024, 0, stream>>>(deg, rowptr);
    scatter_kernel<<<(N_EDGES + 255) / 256, 256, 0, stream>>>(src, dst, rowptr, cursor, ssrc);

    node_kernel<<<(N_NODES + 3) / 4, 256, 0, stream>>>(hb, el, er, rowptr, ssrc, ws_e,
                                                       gat_bias, agg);

    dim3 g2((N_NODES + BM - 1) / BM, OUT_DIM / BN);
    gemm_f32<0><<<g2, blk, 0, stream>>>(agg, lin_W, out, N_NODES, HD, OUT_DIM, lin_b, 1);
}

// Round 3
// 477.032 us; speedup vs baseline: 1.5152x; 1.3167x over previous
//
#include <hip/hip_runtime.h>

#define N_NODES 100000
#define N_EDGES 1600000
#define IN_DIM 256
#define HID 64
#define HEADS 2
#define HD 128
#define OUT_DIM 256
#define NEG_SLOPE 0.2f

typedef unsigned int uint32;
typedef unsigned short ushort16;

__device__ __forceinline__ ushort16 f2bf(float f) {
    union { float f; uint32 u; } v; v.f = f;
    uint32 u = v.u;
    return (ushort16)((u + 0x7FFFu + ((u >> 16) & 1u)) >> 16);  // RNE
}
__device__ __forceinline__ float bf2f(ushort16 b) {
    union { uint32 u; float f; } v; v.u = ((uint32)b) << 16;
    return v.f;
}

// ---------------- GEMM: C[M,N] = A[M,K] @ B[K,N] (+bias, relu) ----------------
#define BM 128
#define BN 128
#define BK 32
#define APAD 4

template <int BF16OUT>
__global__ __launch_bounds__(256)
void gemm_f32(const float* __restrict__ A, const float* __restrict__ B,
              void* __restrict__ Cout, int M, int K, int N,
              const float* __restrict__ bias, int relu_flag)
{
    __shared__ float As[BK * (BM + APAD)];   // transposed: As[kk][m]
    __shared__ float Bs[BK * BN];            // Bs[kk][n]
    const int t  = threadIdx.x;
    const int tx = t & 15;
    const int ty = t >> 4;
    const int m0 = blockIdx.x * BM;
    const int n0 = blockIdx.y * BN;

    float acc[8][8];
#pragma unroll
    for (int i = 0; i < 8; i++)
#pragma unroll
        for (int j = 0; j < 8; j++) acc[i][j] = 0.f;

    for (int k0 = 0; k0 < K; k0 += BK) {
#pragma unroll
        for (int i = 0; i < 4; i++) {
            int f = t + i * 256;
            int r = f >> 3;
            int c = (f & 7) * 4;
            int gr = m0 + r;
            if (gr > M - 1) gr = M - 1;
            float4 v = *reinterpret_cast<const float4*>(&A[(size_t)gr * K + k0 + c]);
            As[(c + 0) * (BM + APAD) + r] = v.x;
            As[(c + 1) * (BM + APAD) + r] = v.y;
            As[(c + 2) * (BM + APAD) + r] = v.z;
            As[(c + 3) * (BM + APAD) + r] = v.w;
        }
#pragma unroll
        for (int i = 0; i < 4; i++) {
            int f  = t + i * 256;
            int kk = f >> 5;
            int n4 = (f & 31) * 4;
            *reinterpret_cast<float4*>(&Bs[kk * BN + n4]) =
                *reinterpret_cast<const float4*>(&B[(size_t)(k0 + kk) * N + n0 + n4]);
        }
        __syncthreads();
#pragma unroll
        for (int kk = 0; kk < BK; kk++) {
            float4 a0 = *reinterpret_cast<const float4*>(&As[kk * (BM + APAD) + ty * 4]);
            float4 a1 = *reinterpret_cast<const float4*>(&As[kk * (BM + APAD) + 64 + ty * 4]);
            float4 b0 = *reinterpret_cast<const float4*>(&Bs[kk * BN + tx * 4]);
            float4 b1 = *reinterpret_cast<const float4*>(&Bs[kk * BN + 64 + tx * 4]);
            float a[8] = {a0.x, a0.y, a0.z, a0.w, a1.x, a1.y, a1.z, a1.w};
            float b[8] = {b0.x, b0.y, b0.z, b0.w, b1.x, b1.y, b1.z, b1.w};
#pragma unroll
            for (int i = 0; i < 8; i++)
#pragma unroll
                for (int j = 0; j < 8; j++)
                    acc[i][j] = fmaf(a[i], b[j], acc[i][j]);
        }
        __syncthreads();
    }

#pragma unroll
    for (int i = 0; i < 8; i++) {
        int row = m0 + ((i < 4) ? (ty * 4 + i) : (64 + ty * 4 + i - 4));
        if (row >= M) continue;
#pragma unroll
        for (int cj = 0; cj < 2; cj++) {
            int col = n0 + ((cj == 0) ? tx * 4 : 64 + tx * 4);
            float4 v;
            v.x = acc[i][cj * 4 + 0];
            v.y = acc[i][cj * 4 + 1];
            v.z = acc[i][cj * 4 + 2];
            v.w = acc[i][cj * 4 + 3];
            if (bias) {
                v.x += bias[col + 0]; v.y += bias[col + 1];
                v.z += bias[col + 2]; v.w += bias[col + 3];
            }
            if (relu_flag) {
                v.x = fmaxf(v.x, 0.f); v.y = fmaxf(v.y, 0.f);
                v.z = fmaxf(v.z, 0.f); v.w = fmaxf(v.w, 0.f);
            }
            if (BF16OUT) {
                ushort16* C = (ushort16*)Cout;
                uint2 p;
                p.x = (uint32)f2bf(v.x) | ((uint32)f2bf(v.y) << 16);
                p.y = (uint32)f2bf(v.z) | ((uint32)f2bf(v.w) << 16);
                *reinterpret_cast<uint2*>(&C[(size_t)row * N + col]) = p;
            } else {
                float* C = (float*)Cout;
                *reinterpret_cast<float4*>(&C[(size_t)row * N + col]) = v;
            }
        }
    }
}

// ---------------- el/er from bf16 h: one wave per node ----------------
__global__ __launch_bounds__(256)
void elr_kernel(const ushort16* __restrict__ hb, const float* __restrict__ attn_l,
                const float* __restrict__ attn_r, float* __restrict__ el,
                float* __restrict__ er)
{
    int w    = (int)((blockIdx.x * blockDim.x + threadIdx.x) >> 6);
    int lane = threadIdx.x & 63;
    if (w >= N_NODES) return;
    float h0 = bf2f(hb[(size_t)w * HD + lane]);
    float h1 = bf2f(hb[(size_t)w * HD + 64 + lane]);
    float v0 = h0 * attn_l[lane];
    float v1 = h1 * attn_l[64 + lane];
    float v2 = h0 * attn_r[lane];
    float v3 = h1 * attn_r[64 + lane];
#pragma unroll
    for (int o = 32; o; o >>= 1) {
        v0 += __shfl_xor(v0, o);
        v1 += __shfl_xor(v1, o);
        v2 += __shfl_xor(v2, o);
        v3 += __shfl_xor(v3, o);
    }
    if (lane == 0) {
        el[w * 2 + 0] = v0; el[w * 2 + 1] = v1;
        er[w * 2 + 0] = v2; er[w * 2 + 1] = v3;
    }
}

// ---------------- CSR build ----------------
__global__ void deg_kernel(const int* __restrict__ dst, int* __restrict__ deg)
{
    int i = blockIdx.x * blockDim.x + threadIdx.x;
    if (i < N_EDGES) atomicAdd(&deg[dst[i]], 1);
}

// ---- parallel exclusive scan over deg[0..N_NODES) -> row_ptr, 3 kernels ----
#define SCAN_B 1024
#define SCAN_NB ((N_NODES + SCAN_B - 1) / SCAN_B)   // 98

__global__ __launch_bounds__(SCAN_B)
void scan_part(const int* __restrict__ deg, int* __restrict__ row_ptr,
               int* __restrict__ bsum)
{
    __shared__ int sdata[SCAN_B];
    const int t = threadIdx.x, b = blockIdx.x;
    const int i = b * SCAN_B + t;
    int v = (i < N_NODES) ? deg[i] : 0;
    sdata[t] = v;
    __syncthreads();
    for (int off = 1; off < SCAN_B; off <<= 1) {
        int x = 0;
        if (t >= off) x = sdata[t - off];
        __syncthreads();
        sdata[t] += x;
        __syncthreads();
    }
    if (i < N_NODES) row_ptr[i] = sdata[t] - v;      // block-local exclusive
    if (t == SCAN_B - 1) bsum[b] = sdata[t];
}

__global__ __launch_bounds__(128)
void scan_top(int* __restrict__ bsum, int* __restrict__ row_ptr)
{
    __shared__ int sdata[128];
    const int t = threadIdx.x;
    int v = (t < SCAN_NB) ? bsum[t] : 0;
    sdata[t] = v;
    __syncthreads();
    for (int off = 1; off < 128; off <<= 1) {
        int x = 0;
        if (t >= off) x = sdata[t - off];
        __syncthreads();
        sdata[t] += x;
        __syncthreads();
    }
    if (t < SCAN_NB) bsum[t] = sdata[t] - v;         // exclusive block offsets
    if (t == 127) row_ptr[N_NODES] = sdata[127];     // total = N_EDGES
}

__global__ __launch_bounds__(SCAN_B)
void scan_add(int* __restrict__ row_ptr, const int* __restrict__ bsum)
{
    const int i = blockIdx.x * SCAN_B + threadIdx.x;
    if (i < N_NODES) row_ptr[i] += bsum[blockIdx.x];
}

__global__ void scatter_kernel(const int* __restrict__ src, const int* __restrict__ dst,
                               const int* __restrict__ row_ptr, int* __restrict__ cursor,
                               int* __restrict__ sorted_src)
{
    int i = blockIdx.x * blockDim.x + threadIdx.x;
    if (i < N_EDGES) {
        int d = dst[i];
        int p = row_ptr[d] + atomicAdd(&cursor[d], 1);
        sorted_src[p] = src[i];
    }
}

// ---------------- per-node softmax + aggregation: one wave per node ----------------
__global__ __launch_bounds__(256)
void node_kernel(const ushort16* __restrict__ hb, const float* __restrict__ el,
                 const float* __restrict__ er, const int* __restrict__ row_ptr,
                 const int* __restrict__ sorted_src, float* __restrict__ ws_e,
                 const float* __restrict__ gat_bias, float* __restrict__ agg)
{
    int n    = (int)((blockIdx.x * blockDim.x + threadIdx.x) >> 6);
    int lane = threadIdx.x & 63;
    if (n >= N_NODES) return;
    int beg = row_ptr[n], end = row_ptr[n + 1];

    float er0 = er[n * 2 + 0], er1 = er[n * 2 + 1];

    // phase 1: logits (stored raw) + online max/sum per lane
    float mx0 = -1e30f, mx1 = -1e30f, s0 = 0.f, s1 = 0.f;
    for (int i = beg + lane; i < end; i += 64) {
        int s = sorted_src[i];
        float2 elv = *reinterpret_cast<const float2*>(&el[s * 2]);
        float e0 = elv.x + er0; e0 = e0 > 0.f ? e0 : NEG_SLOPE * e0;
        float e1 = elv.y + er1; e1 = e1 > 0.f ? e1 : NEG_SLOPE * e1;
        float2 st; st.x = e0; st.y = e1;
        *reinterpret_cast<float2*>(&ws_e[(size_t)i * 2]) = st;
        float m0n = fmaxf(mx0, e0);
        s0 = s0 * __expf(mx0 - m0n) + __expf(e0 - m0n);
        mx0 = m0n;
        float m1n = fmaxf(mx1, e1);
        s1 = s1 * __expf(mx1 - m1n) + __expf(e1 - m1n);
        mx1 = m1n;
    }
    // cross-lane online-softmax merge
#pragma unroll
    for (int o = 32; o; o >>= 1) {
        float mo0 = __shfl_xor(mx0, o);
        float so0 = __shfl_xor(s0, o);
        float m0  = fmaxf(mx0, mo0);
        s0 = s0 * __expf(mx0 - m0) + so0 * __expf(mo0 - m0);
        mx0 = m0;
        float mo1 = __shfl_xor(mx1, o);
        float so1 = __shfl_xor(s1, o);
        float m1  = fmaxf(mx1, mo1);
        s1 = s1 * __expf(mx1 - m1) + so1 * __expf(mo1 - m1);
        mx1 = m1;
    }
    __threadfence_block();   // ws_e stores visible across lanes

    float inv0 = s0 > 0.f ? 1.f / s0 : 0.f;
    float inv1 = s1 > 0.f ? 1.f / s1 : 0.f;

    // phase 3: half-wave edge split. 32 lanes cover 128 dims (4 bf16 each).
    const int half = lane >> 5;
    const int j    = lane & 31;
    const bool hd1 = (j >= 16);
    const float mxh  = hd1 ? mx1 : mx0;
    const float invh = hd1 ? inv1 : inv0;
    float4 acc = {0.f, 0.f, 0.f, 0.f};

    int e = beg + half;
#define EDGE_BODY(E)                                                              \
    {                                                                             \
        float2 ev = *reinterpret_cast<const float2*>(&ws_e[(size_t)(E) * 2]);     \
        int s = sorted_src[(E)];                                                  \
        float a = __expf((hd1 ? ev.y : ev.x) - mxh) * invh;                       \
        uint2 hv = *reinterpret_cast<const uint2*>(&hb[(size_t)s * HD + 4 * j]);  \
        acc.x = fmaf(a, bf2f((ushort16)(hv.x & 0xffff)), acc.x);                  \
        acc.y = fmaf(a, bf2f((ushort16)(hv.x >> 16)),    acc.y);                  \
        acc.z = fmaf(a, bf2f((ushort16)(hv.y & 0xffff)), acc.z);                  \
        acc.w = fmaf(a, bf2f((ushort16)(hv.y >> 16)),    acc.w);                  \
    }
    for (; e + 2 < end; e += 4) { EDGE_BODY(e); EDGE_BODY(e + 2); }
    if (e < end) EDGE_BODY(e);
#undef EDGE_BODY

    // combine the two half-waves
    acc.x += __shfl_xor(acc.x, 32);
    acc.y += __shfl_xor(acc.y, 32);
    acc.z += __shfl_xor(acc.z, 32);
    acc.w += __shfl_xor(acc.w, 32);

    if (lane < 32) {
        float4 b = *reinterpret_cast<const float4*>(&gat_bias[4 * j]);
        float4 o;
        o.x = fmaxf(acc.x + b.x, 0.f);
        o.y = fmaxf(acc.y + b.y, 0.f);
        o.z = fmaxf(acc.z + b.z, 0.f);
        o.w = fmaxf(acc.w + b.w, 0.f);
        *reinterpret_cast<float4*>(&agg[(size_t)n * HD + 4 * j]) = o;
    }
}

// ---------------- launch ----------------
extern "C" void kernel_launch(void* const* d_in, const int* in_sizes, int n_in,
                              void* d_out, int out_size, void* d_ws, size_t ws_size,
                              hipStream_t stream)
{
    const float* feat     = (const float*)d_in[0];
    const int*   src      = (const int*)d_in[1];
    const int*   dst      = (const int*)d_in[2];
    const float* W        = (const float*)d_in[3];
    const float* attn_l   = (const float*)d_in[4];
    const float* attn_r   = (const float*)d_in[5];
    const float* gat_bias = (const float*)d_in[6];
    const float* lin_W    = (const float*)d_in[7];
    const float* lin_b    = (const float*)d_in[8];
    float* out = (float*)d_out;

    char* ws = (char*)d_ws;
    ushort16* hb  = (ushort16*)(ws + 0);          // 25,600,000 B
    float* agg    = (float*)(ws + 25600000);      // 51,200,000 B
    float* ws_e   = (float*)(ws + 76800000);      // 12,800,000 B
    int*   ssrc   = (int*)  (ws + 89600000);      //  6,400,000 B
    float* el     = (float*)(ws + 96000000);      //    800,000 B
    float* er     = (float*)(ws + 96800000);      //    800,000 B
    int*   deg    = (int*)  (ws + 97600000);      //    400,000 B
    int*   cursor = (int*)  (ws + 98000000);      //    400,000 B
    int*   rowptr = (int*)  (ws + 98400000);      //    400,004 B
    int*   bsum   = (int*)  (ws + 98800128);      //        392 B

    hipMemsetAsync(deg, 0, 800000, stream);       // deg + cursor

    dim3 blk(256);
    dim3 g1((N_NODES + BM - 1) / BM, 1);
    gemm_f32<1><<<g1, blk, 0, stream>>>(feat, W, hb, N_NODES, IN_DIM, HD, nullptr, 0);

    elr_kernel<<<(N_NODES + 3) / 4, 256, 0, stream>>>(hb, attn_l, attn_r, el, er);

    deg_kernel<<<(N_EDGES + 255) / 256, 256, 0, stream>>>(dst, deg);
    scan_part<<<SCAN_NB, SCAN_B, 0, stream>>>(deg, rowptr, bsum);
    scan_top<<<1, 128, 0, stream>>>(bsum, rowptr);
    scan_add<<<SCAN_NB, SCAN_B, 0, stream>>>(rowptr, bsum);
    scatter_kernel<<<(N_EDGES + 255) / 256, 256, 0, stream>>>(src, dst, rowptr, cursor, ssrc);

    node_kernel<<<(N_NODES + 3) / 4, 256, 0, stream>>>(hb, el, er, rowptr, ssrc, ws_e,
                                                       gat_bias, agg);

    dim3 g2((N_NODES + BM - 1) / BM, OUT_DIM / BN);
    gemm_f32<0><<<g2, blk, 0, stream>>>(agg, lin_W, out, N_NODES, HD, OUT_DIM, lin_b, 1);
}

// Round 4
// 379.984 us; speedup vs baseline: 1.9021x; 1.2554x over previous
//
#include <hip/hip_runtime.h>

#define N_NODES 100000
#define N_EDGES 1600000
#define IN_DIM 256
#define HID 64
#define HEADS 2
#define HD 128
#define OUT_DIM 256
#define NEG_SLOPE 0.2f

typedef unsigned int uint32;
typedef unsigned short ushort16;
typedef __attribute__((ext_vector_type(8))) short bf16x8;
typedef __attribute__((ext_vector_type(4))) float f32x4;

__device__ __forceinline__ ushort16 f2bf(float f) {
    union { float f; uint32 u; } v; v.f = f;
    uint32 u = v.u;
    return (ushort16)((u + 0x7FFFu + ((u >> 16) & 1u)) >> 16);  // RNE
}
__device__ __forceinline__ float bf2f(ushort16 b) {
    union { uint32 u; float f; } v; v.u = ((uint32)b) << 16;
    return v.f;
}

// ---------- weight transpose+convert: Wt1[n][k] = bf16(W[k][n]) ----------
__global__ __launch_bounds__(256)
void conv_w1(const float* __restrict__ W, ushort16* __restrict__ Wt)
{   // W [256][128] -> Wt [128][256]
    int idx = blockIdx.x * 256 + threadIdx.x;
    int n = idx >> 8, k = idx & 255;
    Wt[idx] = f2bf(W[k * HD + n]);
}
__global__ __launch_bounds__(256)
void conv_w2(const float* __restrict__ W, ushort16* __restrict__ Wt)
{   // lin_W [128][256] -> Wt [256][128]
    int idx = blockIdx.x * 256 + threadIdx.x;
    int n = idx >> 7, k = idx & 127;
    Wt[idx] = f2bf(W[k * OUT_DIM + n]);
}

// ---------------- GEMM1: hb[M,128] = bf16(feat[M,256] @ W) via MFMA ----------------
__global__ __launch_bounds__(256)
void gemm1_mfma(const float* __restrict__ A, const ushort16* __restrict__ Bt,
                ushort16* __restrict__ C, int M)
{
    __shared__ char alds[2 * 16384];   // dbuf 128x64 bf16, XOR-swizzled
    const int t    = threadIdx.x;
    const int lane = t & 63;
    const int w    = t >> 6;
    const int wr   = w >> 1, wc = w & 1;
    const int m0   = blockIdx.x * 128;
    const int l15  = lane & 15;
    const int lq   = lane >> 4;

    f32x4 acc[4][4] = {};
    float4 av[8];

#define G1_LOAD(KT)                                                               \
    {                                                                             \
        _Pragma("unroll")                                                         \
        for (int i = 0; i < 8; i++) {                                             \
            int flat = t + i * 256;                                               \
            int r = flat >> 4, kq = (flat & 15) * 4;                              \
            int gr = m0 + r; if (gr >= M) gr = M - 1;                             \
            av[i] = *reinterpret_cast<const float4*>(                             \
                        &A[(size_t)gr * IN_DIM + (KT) * 64 + kq]);                \
        }                                                                         \
    }
#define G1_WRITE(BUF)                                                             \
    {                                                                             \
        _Pragma("unroll")                                                         \
        for (int i = 0; i < 8; i++) {                                             \
            int flat = t + i * 256;                                               \
            int r = flat >> 4, kq = (flat & 15) * 4;                              \
            uint2 p;                                                              \
            p.x = (uint32)f2bf(av[i].x) | ((uint32)f2bf(av[i].y) << 16);          \
            p.y = (uint32)f2bf(av[i].z) | ((uint32)f2bf(av[i].w) << 16);          \
            int byte = (r * 128 + kq * 2) ^ ((r & 7) << 4);                       \
            *reinterpret_cast<uint2*>(&alds[(BUF) * 16384 + byte]) = p;           \
        }                                                                         \
    }

    G1_LOAD(0); G1_WRITE(0);
    __syncthreads();
    int cur = 0;
    for (int kt = 0; kt < 4; kt++) {
        if (kt < 3) G1_LOAD(kt + 1);
        bf16x8 bfr[2][4];
#pragma unroll
        for (int ks = 0; ks < 2; ks++)
#pragma unroll
            for (int nf = 0; nf < 4; nf++) {
                int col = wc * 64 + nf * 16 + l15;
                int kb  = (kt * 2 + ks) * 32 + lq * 8;
                bfr[ks][nf] = *reinterpret_cast<const bf16x8*>(&Bt[(size_t)col * 256 + kb]);
            }
#pragma unroll
        for (int ks = 0; ks < 2; ks++) {
            bf16x8 afr[4];
#pragma unroll
            for (int mf = 0; mf < 4; mf++) {
                int row  = wr * 64 + mf * 16 + l15;
                int byte = (row * 128 + ks * 64 + lq * 16) ^ ((row & 7) << 4);
                afr[mf] = *reinterpret_cast<const bf16x8*>(&alds[cur * 16384 + byte]);
            }
#pragma unroll
            for (int mf = 0; mf < 4; mf++)
#pragma unroll
                for (int nf = 0; nf < 4; nf++)
                    acc[mf][nf] = __builtin_amdgcn_mfma_f32_16x16x32_bf16(
                        afr[mf], bfr[ks][nf], acc[mf][nf], 0, 0, 0);
        }
        if (kt < 3) G1_WRITE(cur ^ 1);
        __syncthreads();
        cur ^= 1;
    }
#pragma unroll
    for (int mf = 0; mf < 4; mf++)
#pragma unroll
        for (int nf = 0; nf < 4; nf++)
#pragma unroll
            for (int q = 0; q < 4; q++) {
                int row = m0 + wr * 64 + mf * 16 + lq * 4 + q;
                int col = wc * 64 + nf * 16 + l15;
                if (row < M) C[(size_t)row * HD + col] = f2bf(acc[mf][nf][q]);
            }
#undef G1_LOAD
#undef G1_WRITE
}

// ---------------- GEMM2: out = relu(（agg_hi+agg_lo)@lin_W + b) via MFMA ----------------
__global__ __launch_bounds__(256)
void gemm2_mfma(const ushort16* __restrict__ Ahi, const ushort16* __restrict__ Alo,
                const ushort16* __restrict__ Bt, const float* __restrict__ bias,
                float* __restrict__ Cout, int M)
{
    __shared__ char alds[2 * 32768];   // hi tile + lo tile, full K=128, swizzled
    const int t    = threadIdx.x;
    const int lane = t & 63;
    const int w    = t >> 6;
    const int wr   = w >> 1, wc = w & 1;
    const int m0   = blockIdx.x * 128;
    const int n0   = blockIdx.y * 128;
    const int l15  = lane & 15;
    const int lq   = lane >> 4;

    f32x4 acc[4][4] = {};

    // stage hi then lo (coalesced uint4 bf16 loads)
#pragma unroll
    for (int p = 0; p < 2; p++) {
        const ushort16* src = p ? Alo : Ahi;
#pragma unroll
        for (int i = 0; i < 8; i++) {
            int flat = t + i * 256;
            int r = flat >> 4, e8 = (flat & 15) * 8;
            int gr = m0 + r; if (gr >= M) gr = M - 1;
            uint4 v = *reinterpret_cast<const uint4*>(&src[(size_t)gr * HD + e8]);
            int byte = (r * 256 + e8 * 2) ^ ((r & 7) << 4);
            *reinterpret_cast<uint4*>(&alds[p * 32768 + byte]) = v;
        }
    }
    // all B fragments in registers (L2-resident Wt2)
    bf16x8 bfr[4][4];
#pragma unroll
    for (int ks = 0; ks < 4; ks++)
#pragma unroll
        for (int nf = 0; nf < 4; nf++) {
            int col = n0 + wc * 64 + nf * 16 + l15;
            int kb  = ks * 32 + lq * 8;
            bfr[ks][nf] = *reinterpret_cast<const bf16x8*>(&Bt[(size_t)col * HD + kb]);
        }
    __syncthreads();

#pragma unroll
    for (int pass = 0; pass < 2; pass++) {
#pragma unroll
        for (int ks = 0; ks < 4; ks++) {
            bf16x8 afr[4];
#pragma unroll
            for (int mf = 0; mf < 4; mf++) {
                int row  = wr * 64 + mf * 16 + l15;
                int byte = (row * 256 + ks * 64 + lq * 16) ^ ((row & 7) << 4);
                afr[mf] = *reinterpret_cast<const bf16x8*>(&alds[pass * 32768 + byte]);
            }
#pragma unroll
            for (int mf = 0; mf < 4; mf++)
#pragma unroll
                for (int nf = 0; nf < 4; nf++)
                    acc[mf][nf] = __builtin_amdgcn_mfma_f32_16x16x32_bf16(
                        afr[mf], bfr[ks][nf], acc[mf][nf], 0, 0, 0);
        }
    }

    float bias_v[4];
#pragma unroll
    for (int nf = 0; nf < 4; nf++) bias_v[nf] = bias[n0 + wc * 64 + nf * 16 + l15];
#pragma unroll
    for (int mf = 0; mf < 4; mf++)
#pragma unroll
        for (int nf = 0; nf < 4; nf++)
#pragma unroll
            for (int q = 0; q < 4; q++) {
                int row = m0 + wr * 64 + mf * 16 + lq * 4 + q;
                int col = n0 + wc * 64 + nf * 16 + l15;
                if (row < M)
                    Cout[(size_t)row * OUT_DIM + col] = fmaxf(acc[mf][nf][q] + bias_v[nf], 0.f);
            }
}

// ---------------- el/er from bf16 h: one wave per node ----------------
__global__ __launch_bounds__(256)
void elr_kernel(const ushort16* __restrict__ hb, const float* __restrict__ attn_l,
                const float* __restrict__ attn_r, float* __restrict__ el,
                float* __restrict__ er)
{
    int w    = (int)((blockIdx.x * blockDim.x + threadIdx.x) >> 6);
    int lane = threadIdx.x & 63;
    if (w >= N_NODES) return;
    float h0 = bf2f(hb[(size_t)w * HD + lane]);
    float h1 = bf2f(hb[(size_t)w * HD + 64 + lane]);
    float v0 = h0 * attn_l[lane];
    float v1 = h1 * attn_l[64 + lane];
    float v2 = h0 * attn_r[lane];
    float v3 = h1 * attn_r[64 + lane];
#pragma unroll
    for (int o = 32; o; o >>= 1) {
        v0 += __shfl_xor(v0, o);
        v1 += __shfl_xor(v1, o);
        v2 += __shfl_xor(v2, o);
        v3 += __shfl_xor(v3, o);
    }
    if (lane == 0) {
        el[w * 2 + 0] = v0; el[w * 2 + 1] = v1;
        er[w * 2 + 0] = v2; er[w * 2 + 1] = v3;
    }
}

// ---------------- CSR build ----------------
__global__ void deg_kernel(const int* __restrict__ dst, int* __restrict__ deg)
{
    int i = blockIdx.x * blockDim.x + threadIdx.x;
    if (i < N_EDGES) atomicAdd(&deg[dst[i]], 1);
}

#define SCAN_B 1024
#define SCAN_NB ((N_NODES + SCAN_B - 1) / SCAN_B)   // 98

__global__ __launch_bounds__(SCAN_B)
void scan_part(const int* __restrict__ deg, int* __restrict__ row_ptr,
               int* __restrict__ bsum)
{
    __shared__ int sdata[SCAN_B];
    const int t = threadIdx.x, b = blockIdx.x;
    const int i = b * SCAN_B + t;
    int v = (i < N_NODES) ? deg[i] : 0;
    sdata[t] = v;
    __syncthreads();
    for (int off = 1; off < SCAN_B; off <<= 1) {
        int x = 0;
        if (t >= off) x = sdata[t - off];
        __syncthreads();
        sdata[t] += x;
        __syncthreads();
    }
    if (i < N_NODES) row_ptr[i] = sdata[t] - v;
    if (t == SCAN_B - 1) bsum[b] = sdata[t];
}

__global__ __launch_bounds__(128)
void scan_top(int* __restrict__ bsum, int* __restrict__ row_ptr)
{
    __shared__ int sdata[128];
    const int t = threadIdx.x;
    int v = (t < SCAN_NB) ? bsum[t] : 0;
    sdata[t] = v;
    __syncthreads();
    for (int off = 1; off < 128; off <<= 1) {
        int x = 0;
        if (t >= off) x = sdata[t - off];
        __syncthreads();
        sdata[t] += x;
        __syncthreads();
    }
    if (t < SCAN_NB) bsum[t] = sdata[t] - v;
    if (t == 127) row_ptr[N_NODES] = sdata[127];
}

__global__ __launch_bounds__(SCAN_B)
void scan_add(int* __restrict__ row_ptr, const int* __restrict__ bsum)
{
    const int i = blockIdx.x * SCAN_B + threadIdx.x;
    if (i < N_NODES) row_ptr[i] += bsum[blockIdx.x];
}

__global__ void scatter_kernel(const int* __restrict__ src, const int* __restrict__ dst,
                               const int* __restrict__ row_ptr, int* __restrict__ cursor,
                               int* __restrict__ sorted_src)
{
    int i = blockIdx.x * blockDim.x + threadIdx.x;
    if (i < N_EDGES) {
        int d = dst[i];
        int p = row_ptr[d] + atomicAdd(&cursor[d], 1);
        sorted_src[p] = src[i];
    }
}

// ---------------- per-node softmax + aggregation: one wave per node ----------------
__global__ __launch_bounds__(256)
void node_kernel(const ushort16* __restrict__ hb, const float* __restrict__ el,
                 const float* __restrict__ er, const int* __restrict__ row_ptr,
                 const int* __restrict__ sorted_src, float* __restrict__ ws_e,
                 const float* __restrict__ gat_bias,
                 ushort16* __restrict__ agg_hi, ushort16* __restrict__ agg_lo)
{
    int n    = (int)((blockIdx.x * blockDim.x + threadIdx.x) >> 6);
    int lane = threadIdx.x & 63;
    if (n >= N_NODES) return;
    int beg = row_ptr[n], end = row_ptr[n + 1];

    float er0 = er[n * 2 + 0], er1 = er[n * 2 + 1];

    float mx0 = -1e30f, mx1 = -1e30f, s0 = 0.f, s1 = 0.f;
    for (int i = beg + lane; i < end; i += 64) {
        int s = sorted_src[i];
        float2 elv = *reinterpret_cast<const float2*>(&el[s * 2]);
        float e0 = elv.x + er0; e0 = e0 > 0.f ? e0 : NEG_SLOPE * e0;
        float e1 = elv.y + er1; e1 = e1 > 0.f ? e1 : NEG_SLOPE * e1;
        float2 st; st.x = e0; st.y = e1;
        *reinterpret_cast<float2*>(&ws_e[(size_t)i * 2]) = st;
        float m0n = fmaxf(mx0, e0);
        s0 = s0 * __expf(mx0 - m0n) + __expf(e0 - m0n);
        mx0 = m0n;
        float m1n = fmaxf(mx1, e1);
        s1 = s1 * __expf(mx1 - m1n) + __expf(e1 - m1n);
        mx1 = m1n;
    }
#pragma unroll
    for (int o = 32; o; o >>= 1) {
        float mo0 = __shfl_xor(mx0, o);
        float so0 = __shfl_xor(s0, o);
        float m0  = fmaxf(mx0, mo0);
        s0 = s0 * __expf(mx0 - m0) + so0 * __expf(mo0 - m0);
        mx0 = m0;
        float mo1 = __shfl_xor(mx1, o);
        float so1 = __shfl_xor(s1, o);
        float m1  = fmaxf(mx1, mo1);
        s1 = s1 * __expf(mx1 - m1) + so1 * __expf(mo1 - m1);
        mx1 = m1;
    }
    __threadfence_block();

    float inv0 = s0 > 0.f ? 1.f / s0 : 0.f;
    float inv1 = s1 > 0.f ? 1.f / s1 : 0.f;

    const int half = lane >> 5;
    const int j    = lane & 31;
    const bool hd1 = (j >= 16);
    const float mxh  = hd1 ? mx1 : mx0;
    const float invh = hd1 ? inv1 : inv0;
    float4 acc = {0.f, 0.f, 0.f, 0.f};

    int e = beg + half;
#define EDGE_BODY(E)                                                              \
    {                                                                             \
        float2 ev = *reinterpret_cast<const float2*>(&ws_e[(size_t)(E) * 2]);     \
        int s = sorted_src[(E)];                                                  \
        float a = __expf((hd1 ? ev.y : ev.x) - mxh) * invh;                       \
        uint2 hv = *reinterpret_cast<const uint2*>(&hb[(size_t)s * HD + 4 * j]);  \
        acc.x = fmaf(a, bf2f((ushort16)(hv.x & 0xffff)), acc.x);                  \
        acc.y = fmaf(a, bf2f((ushort16)(hv.x >> 16)),    acc.y);                  \
        acc.z = fmaf(a, bf2f((ushort16)(hv.y & 0xffff)), acc.z);                  \
        acc.w = fmaf(a, bf2f((ushort16)(hv.y >> 16)),    acc.w);                  \
    }
    for (; e + 2 < end; e += 4) { EDGE_BODY(e); EDGE_BODY(e + 2); }
    if (e < end) EDGE_BODY(e);
#undef EDGE_BODY

    acc.x += __shfl_xor(acc.x, 32);
    acc.y += __shfl_xor(acc.y, 32);
    acc.z += __shfl_xor(acc.z, 32);
    acc.w += __shfl_xor(acc.w, 32);

    if (lane < 32) {
        float4 b = *reinterpret_cast<const float4*>(&gat_bias[4 * j]);
        float o[4];
        o[0] = fmaxf(acc.x + b.x, 0.f);
        o[1] = fmaxf(acc.y + b.y, 0.f);
        o[2] = fmaxf(acc.z + b.z, 0.f);
        o[3] = fmaxf(acc.w + b.w, 0.f);
        ushort16 hi[4], lo[4];
#pragma unroll
        for (int q = 0; q < 4; q++) {
            hi[q] = f2bf(o[q]);
            lo[q] = f2bf(o[q] - bf2f(hi[q]));
        }
        uint2 ph, pl;
        ph.x = (uint32)hi[0] | ((uint32)hi[1] << 16);
        ph.y = (uint32)hi[2] | ((uint32)hi[3] << 16);
        pl.x = (uint32)lo[0] | ((uint32)lo[1] << 16);
        pl.y = (uint32)lo[2] | ((uint32)lo[3] << 16);
        *reinterpret_cast<uint2*>(&agg_hi[(size_t)n * HD + 4 * j]) = ph;
        *reinterpret_cast<uint2*>(&agg_lo[(size_t)n * HD + 4 * j]) = pl;
    }
}

// ---------------- launch ----------------
extern "C" void kernel_launch(void* const* d_in, const int* in_sizes, int n_in,
                              void* d_out, int out_size, void* d_ws, size_t ws_size,
                              hipStream_t stream)
{
    const float* feat     = (const float*)d_in[0];
    const int*   src      = (const int*)d_in[1];
    const int*   dst      = (const int*)d_in[2];
    const float* W        = (const float*)d_in[3];
    const float* attn_l   = (const float*)d_in[4];
    const float* attn_r   = (const float*)d_in[5];
    const float* gat_bias = (const float*)d_in[6];
    const float* lin_W    = (const float*)d_in[7];
    const float* lin_b    = (const float*)d_in[8];
    float* out = (float*)d_out;

    char* ws = (char*)d_ws;
    ushort16* hb     = (ushort16*)(ws + 0);          // 25,600,000 B
    ushort16* agg_hi = (ushort16*)(ws + 25600000);   // 25,600,000 B
    ushort16* agg_lo = (ushort16*)(ws + 51200000);   // 25,600,000 B
    float* ws_e   = (float*)(ws + 76800000);         // 12,800,000 B
    int*   ssrc   = (int*)  (ws + 89600000);         //  6,400,000 B
    float* el     = (float*)(ws + 96000000);         //    800,000 B
    float* er     = (float*)(ws + 96800000);         //    800,000 B
    int*   deg    = (int*)  (ws + 97600000);         //    400,000 B
    int*   cursor = (int*)  (ws + 98000000);         //    400,000 B
    int*   rowptr = (int*)  (ws + 98400000);         //    400,004 B
    int*   bsum   = (int*)  (ws + 98800128);         //        392 B
    ushort16* Wt1 = (ushort16*)(ws + 98804608);      //     65,536 B
    ushort16* Wt2 = (ushort16*)(ws + 98870144);      //     65,536 B

    hipMemsetAsync(deg, 0, 800000, stream);          // deg + cursor

    conv_w1<<<128, 256, 0, stream>>>(W, Wt1);
    conv_w2<<<128, 256, 0, stream>>>(lin_W, Wt2);

    dim3 blk(256);
    gemm1_mfma<<<(N_NODES + 127) / 128, blk, 0, stream>>>(feat, Wt1, hb, N_NODES);

    elr_kernel<<<(N_NODES + 3) / 4, 256, 0, stream>>>(hb, attn_l, attn_r, el, er);

    deg_kernel<<<(N_EDGES + 255) / 256, 256, 0, stream>>>(dst, deg);
    scan_part<<<SCAN_NB, SCAN_B, 0, stream>>>(deg, rowptr, bsum);
    scan_top<<<1, 128, 0, stream>>>(bsum, rowptr);
    scan_add<<<SCAN_NB, SCAN_B, 0, stream>>>(rowptr, bsum);
    scatter_kernel<<<(N_EDGES + 255) / 256, 256, 0, stream>>>(src, dst, rowptr, cursor, ssrc);

    node_kernel<<<(N_NODES + 3) / 4, 256, 0, stream>>>(hb, el, er, rowptr, ssrc, ws_e,
                                                       gat_bias, agg_hi, agg_lo);

    dim3 g2((N_NODES + 127) / 128, 2);
    gemm2_mfma<<<g2, blk, 0, stream>>>(agg_hi, agg_lo, Wt2, lin_b, out, N_NODES);
}

// Round 5
// 370.197 us; speedup vs baseline: 1.9524x; 1.0264x over previous
//
#include <hip/hip_runtime.h>

#define N_NODES 100000
#define N_EDGES 1600000
#define IN_DIM 256
#define HID 64
#define HEADS 2
#define HD 128
#define OUT_DIM 256
#define NEG_SLOPE 0.2f

typedef unsigned int uint32;
typedef unsigned short ushort16;
typedef __attribute__((ext_vector_type(8))) short bf16x8;
typedef __attribute__((ext_vector_type(4))) float f32x4;

__device__ __forceinline__ ushort16 f2bf(float f) {
    union { float f; uint32 u; } v; v.f = f;
    uint32 u = v.u;
    return (ushort16)((u + 0x7FFFu + ((u >> 16) & 1u)) >> 16);  // RNE
}
__device__ __forceinline__ float bf2f(ushort16 b) {
    union { uint32 u; float f; } v; v.u = ((uint32)b) << 16;
    return v.f;
}
__device__ __forceinline__ float bflo(uint32 u) {   // low bf16 of a dword
    union { uint32 u; float f; } v; v.u = u << 16;
    return v.f;
}
__device__ __forceinline__ float bfhi(uint32 u) {   // high bf16 of a dword
    union { uint32 u; float f; } v; v.u = u & 0xffff0000u;
    return v.f;
}

// ---------- weight transpose+convert: Wt1[n][k] = bf16(W[k][n]) ----------
__global__ __launch_bounds__(256)
void conv_w1(const float* __restrict__ W, ushort16* __restrict__ Wt)
{   // W [256][128] -> Wt [128][256]
    int idx = blockIdx.x * 256 + threadIdx.x;
    int n = idx >> 8, k = idx & 255;
    Wt[idx] = f2bf(W[k * HD + n]);
}
__global__ __launch_bounds__(256)
void conv_w2(const float* __restrict__ W, ushort16* __restrict__ Wt)
{   // lin_W [128][256] -> Wt [256][128]
    int idx = blockIdx.x * 256 + threadIdx.x;
    int n = idx >> 7, k = idx & 127;
    Wt[idx] = f2bf(W[k * OUT_DIM + n]);
}

// ---------------- GEMM1: hb[M,128] = bf16(feat[M,256] @ W) via MFMA ----------------
__global__ __launch_bounds__(256)
void gemm1_mfma(const float* __restrict__ A, const ushort16* __restrict__ Bt,
                ushort16* __restrict__ C, int M)
{
    __shared__ char alds[2 * 16384];   // dbuf 128x64 bf16, XOR-swizzled
    const int t    = threadIdx.x;
    const int lane = t & 63;
    const int w    = t >> 6;
    const int wr   = w >> 1, wc = w & 1;
    const int m0   = blockIdx.x * 128;
    const int l15  = lane & 15;
    const int lq   = lane >> 4;

    f32x4 acc[4][4] = {};
    float4 av[8];

#define G1_LOAD(KT)                                                               \
    {                                                                             \
        _Pragma("unroll")                                                         \
        for (int i = 0; i < 8; i++) {                                             \
            int flat = t + i * 256;                                               \
            int r = flat >> 4, kq = (flat & 15) * 4;                              \
            int gr = m0 + r; if (gr >= M) gr = M - 1;                             \
            av[i] = *reinterpret_cast<const float4*>(                             \
                        &A[(size_t)gr * IN_DIM + (KT) * 64 + kq]);                \
        }                                                                         \
    }
#define G1_WRITE(BUF)                                                             \
    {                                                                             \
        _Pragma("unroll")                                                         \
        for (int i = 0; i < 8; i++) {                                             \
            int flat = t + i * 256;                                               \
            int r = flat >> 4, kq = (flat & 15) * 4;                              \
            uint2 p;                                                              \
            p.x = (uint32)f2bf(av[i].x) | ((uint32)f2bf(av[i].y) << 16);          \
            p.y = (uint32)f2bf(av[i].z) | ((uint32)f2bf(av[i].w) << 16);          \
            int byte = (r * 128 + kq * 2) ^ ((r & 7) << 4);                       \
            *reinterpret_cast<uint2*>(&alds[(BUF) * 16384 + byte]) = p;           \
        }                                                                         \
    }

    G1_LOAD(0); G1_WRITE(0);
    __syncthreads();
    int cur = 0;
    for (int kt = 0; kt < 4; kt++) {
        if (kt < 3) G1_LOAD(kt + 1);
        bf16x8 bfr[2][4];
#pragma unroll
        for (int ks = 0; ks < 2; ks++)
#pragma unroll
            for (int nf = 0; nf < 4; nf++) {
                int col = wc * 64 + nf * 16 + l15;
                int kb  = (kt * 2 + ks) * 32 + lq * 8;
                bfr[ks][nf] = *reinterpret_cast<const bf16x8*>(&Bt[(size_t)col * 256 + kb]);
            }
#pragma unroll
        for (int ks = 0; ks < 2; ks++) {
            bf16x8 afr[4];
#pragma unroll
            for (int mf = 0; mf < 4; mf++) {
                int row  = wr * 64 + mf * 16 + l15;
                int byte = (row * 128 + ks * 64 + lq * 16) ^ ((row & 7) << 4);
                afr[mf] = *reinterpret_cast<const bf16x8*>(&alds[cur * 16384 + byte]);
            }
#pragma unroll
            for (int mf = 0; mf < 4; mf++)
#pragma unroll
                for (int nf = 0; nf < 4; nf++)
                    acc[mf][nf] = __builtin_amdgcn_mfma_f32_16x16x32_bf16(
                        afr[mf], bfr[ks][nf], acc[mf][nf], 0, 0, 0);
        }
        if (kt < 3) G1_WRITE(cur ^ 1);
        __syncthreads();
        cur ^= 1;
    }
#pragma unroll
    for (int mf = 0; mf < 4; mf++)
#pragma unroll
        for (int nf = 0; nf < 4; nf++)
#pragma unroll
            for (int q = 0; q < 4; q++) {
                int row = m0 + wr * 64 + mf * 16 + lq * 4 + q;
                int col = wc * 64 + nf * 16 + l15;
                if (row < M) C[(size_t)row * HD + col] = f2bf(acc[mf][nf][q]);
            }
#undef G1_LOAD
#undef G1_WRITE
}

// ---------------- GEMM2: out = relu((agg_hi+agg_lo)@lin_W + b) via MFMA ----------------
__global__ __launch_bounds__(256)
void gemm2_mfma(const ushort16* __restrict__ Ahi, const ushort16* __restrict__ Alo,
                const ushort16* __restrict__ Bt, const float* __restrict__ bias,
                float* __restrict__ Cout, int M)
{
    __shared__ char alds[2 * 32768];   // hi tile + lo tile, full K=128, swizzled
    const int t    = threadIdx.x;
    const int lane = t & 63;
    const int w    = t >> 6;
    const int wr   = w >> 1, wc = w & 1;
    const int m0   = blockIdx.x * 128;
    const int n0   = blockIdx.y * 128;
    const int l15  = lane & 15;
    const int lq   = lane >> 4;

    f32x4 acc[4][4] = {};

#pragma unroll
    for (int p = 0; p < 2; p++) {
        const ushort16* src = p ? Alo : Ahi;
#pragma unroll
        for (int i = 0; i < 8; i++) {
            int flat = t + i * 256;
            int r = flat >> 4, e8 = (flat & 15) * 8;
            int gr = m0 + r; if (gr >= M) gr = M - 1;
            uint4 v = *reinterpret_cast<const uint4*>(&src[(size_t)gr * HD + e8]);
            int byte = (r * 256 + e8 * 2) ^ ((r & 7) << 4);
            *reinterpret_cast<uint4*>(&alds[p * 32768 + byte]) = v;
        }
    }
    bf16x8 bfr[4][4];
#pragma unroll
    for (int ks = 0; ks < 4; ks++)
#pragma unroll
        for (int nf = 0; nf < 4; nf++) {
            int col = n0 + wc * 64 + nf * 16 + l15;
            int kb  = ks * 32 + lq * 8;
            bfr[ks][nf] = *reinterpret_cast<const bf16x8*>(&Bt[(size_t)col * HD + kb]);
        }
    __syncthreads();

#pragma unroll
    for (int pass = 0; pass < 2; pass++) {
#pragma unroll
        for (int ks = 0; ks < 4; ks++) {
            bf16x8 afr[4];
#pragma unroll
            for (int mf = 0; mf < 4; mf++) {
                int row  = wr * 64 + mf * 16 + l15;
                int byte = (row * 256 + ks * 64 + lq * 16) ^ ((row & 7) << 4);
                afr[mf] = *reinterpret_cast<const bf16x8*>(&alds[pass * 32768 + byte]);
            }
#pragma unroll
            for (int mf = 0; mf < 4; mf++)
#pragma unroll
                for (int nf = 0; nf < 4; nf++)
                    acc[mf][nf] = __builtin_amdgcn_mfma_f32_16x16x32_bf16(
                        afr[mf], bfr[ks][nf], acc[mf][nf], 0, 0, 0);
        }
    }

    float bias_v[4];
#pragma unroll
    for (int nf = 0; nf < 4; nf++) bias_v[nf] = bias[n0 + wc * 64 + nf * 16 + l15];
#pragma unroll
    for (int mf = 0; mf < 4; mf++)
#pragma unroll
        for (int nf = 0; nf < 4; nf++)
#pragma unroll
            for (int q = 0; q < 4; q++) {
                int row = m0 + wr * 64 + mf * 16 + lq * 4 + q;
                int col = n0 + wc * 64 + nf * 16 + l15;
                if (row < M)
                    Cout[(size_t)row * OUT_DIM + col] = fmaxf(acc[mf][nf][q] + bias_v[nf], 0.f);
            }
}

// ---------------- el/er from bf16 h: one wave per node ----------------
__global__ __launch_bounds__(256)
void elr_kernel(const ushort16* __restrict__ hb, const float* __restrict__ attn_l,
                const float* __restrict__ attn_r, float* __restrict__ el,
                float* __restrict__ er)
{
    int w    = (int)((blockIdx.x * blockDim.x + threadIdx.x) >> 6);
    int lane = threadIdx.x & 63;
    if (w >= N_NODES) return;
    float h0 = bf2f(hb[(size_t)w * HD + lane]);
    float h1 = bf2f(hb[(size_t)w * HD + 64 + lane]);
    float v0 = h0 * attn_l[lane];
    float v1 = h1 * attn_l[64 + lane];
    float v2 = h0 * attn_r[lane];
    float v3 = h1 * attn_r[64 + lane];
#pragma unroll
    for (int o = 32; o; o >>= 1) {
        v0 += __shfl_xor(v0, o);
        v1 += __shfl_xor(v1, o);
        v2 += __shfl_xor(v2, o);
        v3 += __shfl_xor(v3, o);
    }
    if (lane == 0) {
        el[w * 2 + 0] = v0; el[w * 2 + 1] = v1;
        er[w * 2 + 0] = v2; er[w * 2 + 1] = v3;
    }
}

// ---------------- CSR build ----------------
__global__ void deg_kernel(const int* __restrict__ dst, int* __restrict__ deg)
{
    int i = blockIdx.x * blockDim.x + threadIdx.x;
    if (i < N_EDGES) atomicAdd(&deg[dst[i]], 1);
}

#define SCAN_B 1024
#define SCAN_NB ((N_NODES + SCAN_B - 1) / SCAN_B)   // 98

__global__ __launch_bounds__(SCAN_B)
void scan_part(const int* __restrict__ deg, int* __restrict__ row_ptr,
               int* __restrict__ bsum)
{
    __shared__ int sdata[SCAN_B];
    const int t = threadIdx.x, b = blockIdx.x;
    const int i = b * SCAN_B + t;
    int v = (i < N_NODES) ? deg[i] : 0;
    sdata[t] = v;
    __syncthreads();
    for (int off = 1; off < SCAN_B; off <<= 1) {
        int x = 0;
        if (t >= off) x = sdata[t - off];
        __syncthreads();
        sdata[t] += x;
        __syncthreads();
    }
    if (i < N_NODES) row_ptr[i] = sdata[t] - v;
    if (t == SCAN_B - 1) bsum[b] = sdata[t];
}

__global__ __launch_bounds__(128)
void scan_top(int* __restrict__ bsum, int* __restrict__ row_ptr)
{
    __shared__ int sdata[128];
    const int t = threadIdx.x;
    int v = (t < SCAN_NB) ? bsum[t] : 0;
    sdata[t] = v;
    __syncthreads();
    for (int off = 1; off < 128; off <<= 1) {
        int x = 0;
        if (t >= off) x = sdata[t - off];
        __syncthreads();
        sdata[t] += x;
        __syncthreads();
    }
    if (t < SCAN_NB) bsum[t] = sdata[t] - v;
    if (t == 127) row_ptr[N_NODES] = sdata[127];
}

__global__ __launch_bounds__(SCAN_B)
void scan_add(int* __restrict__ row_ptr, const int* __restrict__ bsum)
{
    const int i = blockIdx.x * SCAN_B + threadIdx.x;
    if (i < N_NODES) row_ptr[i] += bsum[blockIdx.x];
}

__global__ void scatter_kernel(const int* __restrict__ src, const int* __restrict__ dst,
                               const int* __restrict__ row_ptr, int* __restrict__ cursor,
                               int* __restrict__ sorted_src)
{
    int i = blockIdx.x * blockDim.x + threadIdx.x;
    if (i < N_EDGES) {
        int d = dst[i];
        int p = row_ptr[d] + atomicAdd(&cursor[d], 1);
        sorted_src[p] = src[i];
    }
}

// ---------------- per-node softmax + aggregation: one wave per node ----------------
__global__ __launch_bounds__(256)
void node_kernel(const ushort16* __restrict__ hb, const float* __restrict__ el,
                 const float* __restrict__ er, const int* __restrict__ row_ptr,
                 const int* __restrict__ sorted_src, float* __restrict__ ws_e,
                 const float* __restrict__ gat_bias,
                 ushort16* __restrict__ agg_hi, ushort16* __restrict__ agg_lo)
{
    int n    = (int)((blockIdx.x * blockDim.x + threadIdx.x) >> 6);
    int lane = threadIdx.x & 63;
    if (n >= N_NODES) return;
    int beg = row_ptr[n], end = row_ptr[n + 1];

    float er0 = er[n * 2 + 0], er1 = er[n * 2 + 1];

    // phase 1: logits (stored raw) + online max/sum per lane
    float mx0 = -1e30f, mx1 = -1e30f, s0 = 0.f, s1 = 0.f;
    for (int i = beg + lane; i < end; i += 64) {
        int s = sorted_src[i];
        float2 elv = *reinterpret_cast<const float2*>(&el[s * 2]);
        float e0 = elv.x + er0; e0 = e0 > 0.f ? e0 : NEG_SLOPE * e0;
        float e1 = elv.y + er1; e1 = e1 > 0.f ? e1 : NEG_SLOPE * e1;
        float2 st; st.x = e0; st.y = e1;
        *reinterpret_cast<float2*>(&ws_e[(size_t)i * 2]) = st;
        float m0n = fmaxf(mx0, e0);
        s0 = s0 * __expf(mx0 - m0n) + __expf(e0 - m0n);
        mx0 = m0n;
        float m1n = fmaxf(mx1, e1);
        s1 = s1 * __expf(mx1 - m1n) + __expf(e1 - m1n);
        mx1 = m1n;
    }
#pragma unroll
    for (int o = 32; o; o >>= 1) {
        float mo0 = __shfl_xor(mx0, o);
        float so0 = __shfl_xor(s0, o);
        float m0  = fmaxf(mx0, mo0);
        s0 = s0 * __expf(mx0 - m0) + so0 * __expf(mo0 - m0);
        mx0 = m0;
        float mo1 = __shfl_xor(mx1, o);
        float so1 = __shfl_xor(s1, o);
        float m1  = fmaxf(mx1, mo1);
        s1 = s1 * __expf(mx1 - m1) + so1 * __expf(mo1 - m1);
        mx1 = m1;
    }

    float inv0 = s0 > 0.f ? 1.f / s0 : 0.f;
    float inv1 = s1 > 0.f ? 1.f / s1 : 0.f;

    // phase 2: overwrite ws_e with alpha (each lane rewrites its own phase-1 slots)
    for (int i = beg + lane; i < end; i += 64) {
        float2 ev = *reinterpret_cast<const float2*>(&ws_e[(size_t)i * 2]);
        float2 av;
        av.x = __expf(ev.x - mx0) * inv0;
        av.y = __expf(ev.y - mx1) * inv1;
        *reinterpret_cast<float2*>(&ws_e[(size_t)i * 2]) = av;
    }
    __threadfence_block();   // alpha stores visible across lanes

    // phase 3: slot layout — slot=lane>>4 owns edge stream, j=lane&15 owns dims 8j..8j+7
    const int slot = lane >> 4;
    const int j    = lane & 15;
    float acc[8] = {0.f, 0.f, 0.f, 0.f, 0.f, 0.f, 0.f, 0.f};

#define EDGE_BODY(E)                                                              \
    {                                                                             \
        float2 av = *reinterpret_cast<const float2*>(&ws_e[(size_t)(E) * 2]);     \
        int s = sorted_src[(E)];                                                  \
        float a = (j < 8) ? av.x : av.y;                                          \
        uint4 hv = *reinterpret_cast<const uint4*>(&hb[(size_t)s * HD + 8 * j]);  \
        acc[0] = fmaf(a, bflo(hv.x), acc[0]);                                     \
        acc[1] = fmaf(a, bfhi(hv.x), acc[1]);                                     \
        acc[2] = fmaf(a, bflo(hv.y), acc[2]);                                     \
        acc[3] = fmaf(a, bfhi(hv.y), acc[3]);                                     \
        acc[4] = fmaf(a, bflo(hv.z), acc[4]);                                     \
        acc[5] = fmaf(a, bfhi(hv.z), acc[5]);                                     \
        acc[6] = fmaf(a, bflo(hv.w), acc[6]);                                     \
        acc[7] = fmaf(a, bfhi(hv.w), acc[7]);                                     \
    }
    int e = beg + slot;
    for (; e + 4 < end; e += 8) { EDGE_BODY(e); EDGE_BODY(e + 4); }
    if (e < end) EDGE_BODY(e);
#undef EDGE_BODY

    // reduce across the 4 slots
#pragma unroll
    for (int q = 0; q < 8; q++) {
        acc[q] += __shfl_xor(acc[q], 16);
        acc[q] += __shfl_xor(acc[q], 32);
    }

    if (lane < 16) {
        float4 b0 = *reinterpret_cast<const float4*>(&gat_bias[8 * j]);
        float4 b1 = *reinterpret_cast<const float4*>(&gat_bias[8 * j + 4]);
        float o[8];
        o[0] = fmaxf(acc[0] + b0.x, 0.f);
        o[1] = fmaxf(acc[1] + b0.y, 0.f);
        o[2] = fmaxf(acc[2] + b0.z, 0.f);
        o[3] = fmaxf(acc[3] + b0.w, 0.f);
        o[4] = fmaxf(acc[4] + b1.x, 0.f);
        o[5] = fmaxf(acc[5] + b1.y, 0.f);
        o[6] = fmaxf(acc[6] + b1.z, 0.f);
        o[7] = fmaxf(acc[7] + b1.w, 0.f);
        uint4 ph, pl;
        ushort16 hi[8], lo[8];
#pragma unroll
        for (int q = 0; q < 8; q++) {
            hi[q] = f2bf(o[q]);
            lo[q] = f2bf(o[q] - bf2f(hi[q]));
        }
        ph.x = (uint32)hi[0] | ((uint32)hi[1] << 16);
        ph.y = (uint32)hi[2] | ((uint32)hi[3] << 16);
        ph.z = (uint32)hi[4] | ((uint32)hi[5] << 16);
        ph.w = (uint32)hi[6] | ((uint32)hi[7] << 16);
        pl.x = (uint32)lo[0] | ((uint32)lo[1] << 16);
        pl.y = (uint32)lo[2] | ((uint32)lo[3] << 16);
        pl.z = (uint32)lo[4] | ((uint32)lo[5] << 16);
        pl.w = (uint32)lo[6] | ((uint32)lo[7] << 16);
        *reinterpret_cast<uint4*>(&agg_hi[(size_t)n * HD + 8 * j]) = ph;
        *reinterpret_cast<uint4*>(&agg_lo[(size_t)n * HD + 8 * j]) = pl;
    }
}

// ---------------- launch ----------------
extern "C" void kernel_launch(void* const* d_in, const int* in_sizes, int n_in,
                              void* d_out, int out_size, void* d_ws, size_t ws_size,
                              hipStream_t stream)
{
    const float* feat     = (const float*)d_in[0];
    const int*   src      = (const int*)d_in[1];
    const int*   dst      = (const int*)d_in[2];
    const float* W        = (const float*)d_in[3];
    const float* attn_l   = (const float*)d_in[4];
    const float* attn_r   = (const float*)d_in[5];
    const float* gat_bias = (const float*)d_in[6];
    const float* lin_W    = (const float*)d_in[7];
    const float* lin_b    = (const float*)d_in[8];
    float* out = (float*)d_out;

    char* ws = (char*)d_ws;
    ushort16* hb     = (ushort16*)(ws + 0);          // 25,600,000 B
    ushort16* agg_hi = (ushort16*)(ws + 25600000);   // 25,600,000 B
    ushort16* agg_lo = (ushort16*)(ws + 51200000);   // 25,600,000 B
    float* ws_e   = (float*)(ws + 76800000);         // 12,800,000 B
    int*   ssrc   = (int*)  (ws + 89600000);         //  6,400,000 B
    float* el     = (float*)(ws + 96000000);         //    800,000 B
    float* er     = (float*)(ws + 96800000);         //    800,000 B
    int*   deg    = (int*)  (ws + 97600000);         //    400,000 B
    int*   cursor = (int*)  (ws + 98000000);         //    400,000 B
    int*   rowptr = (int*)  (ws + 98400000);         //    400,004 B
    int*   bsum   = (int*)  (ws + 98800128);         //        392 B
    ushort16* Wt1 = (ushort16*)(ws + 98804608);      //     65,536 B
    ushort16* Wt2 = (ushort16*)(ws + 98870144);      //     65,536 B

    hipMemsetAsync(deg, 0, 800000, stream);          // deg + cursor

    conv_w1<<<128, 256, 0, stream>>>(W, Wt1);
    conv_w2<<<128, 256, 0, stream>>>(lin_W, Wt2);

    dim3 blk(256);
    gemm1_mfma<<<(N_NODES + 127) / 128, blk, 0, stream>>>(feat, Wt1, hb, N_NODES);

    elr_kernel<<<(N_NODES + 3) / 4, 256, 0, stream>>>(hb, attn_l, attn_r, el, er);

    deg_kernel<<<(N_EDGES + 255) / 256, 256, 0, stream>>>(dst, deg);
    scan_part<<<SCAN_NB, SCAN_B, 0, stream>>>(deg, rowptr, bsum);
    scan_top<<<1, 128, 0, stream>>>(bsum, rowptr);
    scan_add<<<SCAN_NB, SCAN_B, 0, stream>>>(rowptr, bsum);
    scatter_kernel<<<(N_EDGES + 255) / 256, 256, 0, stream>>>(src, dst, rowptr, cursor, ssrc);

    node_kernel<<<(N_NODES + 3) / 4, 256, 0, stream>>>(hb, el, er, rowptr, ssrc, ws_e,
                                                       gat_bias, agg_hi, agg_lo);

    dim3 g2((N_NODES + 127) / 128, 2);
    gemm2_mfma<<<g2, blk, 0, stream>>>(agg_hi, agg_lo, Wt2, lin_b, out, N_NODES);
}